// Round 5
// baseline (34912.476 us; speedup 1.0000x reference)
//
#include <hip/hip_runtime.h>
#include <hip/hip_bf16.h>
#include <stdint.h>

#define SEQ   512
#define NBLK  256

typedef __bf16 bf16_t;
typedef bf16_t bf16x8 __attribute__((ext_vector_type(8)));
typedef bf16_t bf16x4v __attribute__((ext_vector_type(4)));
typedef float  f32x4  __attribute__((ext_vector_type(4)));

// ---- dynamic LDS layout (bytes) ----
#define OFF_WT4   0        // W_in^T packed f32 [8][512][4] (64 KiB)
#define OFF_BIN   65536    // b_in f32[512]
#define OFF_BGT   67584    // b_gate strips for this member (4x32)
#define OFF_WOUT  68096    // W_out[m*32..+32]
#define OFF_XS    68224    // xs f32[8][32]; col 31 = y_prev
#define OFF_UNION 69632    // union{ As0+As1 (32 KiB) | Gs f32[2][64][129] (66 KiB) }
#define SMEM_BYTES 135680
#define GSPLANE   8256     // floats per Gs plane (64*129)

// ctrs layout (ints): [g*32] g<16 group ctr | [576] init bar | [608+x] xslot
// [640] ovf | [672+s] slot_xcd (s<256)

// ---- agent-scope relaxed accessors (lower to sc0+sc1 ops, no cache maint) --
__device__ __forceinline__ uint64_t cload64(const void* p) {
    return __hip_atomic_load((const uint64_t*)p, __ATOMIC_RELAXED, __HIP_MEMORY_SCOPE_AGENT);
}
__device__ __forceinline__ void cstore64(void* p, uint64_t v) {
    __hip_atomic_store((uint64_t*)p, v, __ATOMIC_RELAXED, __HIP_MEMORY_SCOPE_AGENT);
}
__device__ __forceinline__ void cstore32(void* p, uint32_t v) {
    __hip_atomic_store((uint32_t*)p, v, __ATOMIC_RELAXED, __HIP_MEMORY_SCOPE_AGENT);
}
__device__ __forceinline__ void cstoref(float* p, float v) {
    __hip_atomic_store(p, v, __ATOMIC_RELAXED, __HIP_MEMORY_SCOPE_AGENT);
}
__device__ __forceinline__ float cloadf(const float* p) {
    return __hip_atomic_load(p, __ATOMIC_RELAXED, __HIP_MEMORY_SCOPE_AGENT);
}
__device__ __forceinline__ int aadd(int* p, int v) {
    return __hip_atomic_fetch_add(p, v, __ATOMIC_RELAXED, __HIP_MEMORY_SCOPE_AGENT);
}
__device__ __forceinline__ int aload(const int* p) {
    return __hip_atomic_load(p, __ATOMIC_RELAXED, __HIP_MEMORY_SCOPE_AGENT);
}
__device__ __forceinline__ void astore(int* p, int v) {
    __hip_atomic_store(p, v, __ATOMIC_RELAXED, __HIP_MEMORY_SCOPE_AGENT);
}

// global->LDS 16B/lane; aux=1 -> sc0 (bypass L1, served by this XCD's L2)
__device__ __forceinline__ void gload16_sc0(const void* g, void* lds) {
    __builtin_amdgcn_global_load_lds(
        (const __attribute__((address_space(1))) void*)g,
        (__attribute__((address_space(3))) void*)lds, 16, 0, 1);
}

__device__ __forceinline__ float sigmoid_f(float x) { return 1.f / (1.f + __expf(-x)); }
__device__ __forceinline__ float tanh_f(float x)    { float e = __expf(2.f * x); return 1.f - 2.f / (e + 1.f); }

// group-local (16-block) split barrier; relaxed atomics, no cache maintenance
__device__ __forceinline__ void bar_arrive(int* c) {
    __syncthreads();
    if (threadIdx.x == 0) {
        __builtin_amdgcn_s_waitcnt(0);
        __hip_atomic_fetch_add(c, 1, __ATOMIC_RELAXED, __HIP_MEMORY_SCOPE_AGENT);
    }
}
__device__ __forceinline__ void bar_wait(int* c, int target) {
    if (threadIdx.x == 0) {
        while (__hip_atomic_load(c, __ATOMIC_RELAXED, __HIP_MEMORY_SCOPE_AGENT) < target)
            __builtin_amdgcn_s_sleep(1);
    }
    __syncthreads();
}

// ---------------- prep kernels ----------------
__global__ void prep_w(const float* __restrict__ W_ih, const float* __restrict__ W_hh,
                       bf16_t* __restrict__ Wcat) {
    const int j = blockIdx.x;
    for (int k = threadIdx.x; k < 1024; k += 256) {
        float v = (k < 512) ? W_ih[(size_t)j * 512 + k] : W_hh[(size_t)j * 512 + (k - 512)];
        Wcat[(size_t)j * 1024 + k] = (bf16_t)v;
    }
}
__global__ void prep_h0(const float* __restrict__ h0, bf16_t* __restrict__ H0) {
    const int b = blockIdx.x;
    for (int d = threadIdx.x; d < 512; d += 256)
        H0[(size_t)b * 512 + d] = (bf16_t)h0[(size_t)b * 512 + d];
}
__global__ void prep_bias(const float* __restrict__ b_ih, const float* __restrict__ b_hh,
                          float* __restrict__ bg, int* __restrict__ ctrs) {
    int j = blockIdx.x * 256 + threadIdx.x;
    bg[j] = b_ih[j] + b_hh[j];
    if (j < 1024) ctrs[j] = 0;
}

// ---------------- persistent whole-sequence kernel ----------------
// Blocks discover their XCD (HW_REG_XCC_ID), claim a (group,member) slot on
// that XCD; group G owns batch rows [G*128,+128), member m owns d-strip
// [m*32,+32) x 4 gates. XCD-uniform groups use L2-coherent staging (sc0
// loads, plain stores); mixed groups fall back to sc1 (fabric) - correct for
// ANY placement, fast when co-located.
__global__ __launch_bounds__(512, 2) void holstm_persist(
    const float* __restrict__ x,     const float* __restrict__ y0,
    const float* __restrict__ c0,    const float* __restrict__ W_in,
    const float* __restrict__ b_in,  const float* __restrict__ b_out,
    const float* __restrict__ W_out, const bf16_t* __restrict__ Wcat,
    const float* __restrict__ bgate, bf16_t* __restrict__ X0g,
    bf16_t* __restrict__ Hb0,        bf16_t* __restrict__ Hb1,
    float* __restrict__ out,         int* __restrict__ ctrs)
{
    extern __shared__ char smem[];
    float* WT4  = (float*)(smem + OFF_WT4);
    float* BIN  = (float*)(smem + OFF_BIN);
    float* BGT  = (float*)(smem + OFF_BGT);
    float* WOUT = (float*)(smem + OFF_WOUT);
    float* XS   = (float*)(smem + OFF_XS);
    char*  UNI  = smem + OFF_UNION;
    float* GS   = (float*)UNI;
    __shared__ int sh_si[2];

    const int tid = threadIdx.x;
    const int l   = tid & 63;
    const int w   = tid >> 6;
    const int r   = l & 15;
    const int q   = l >> 4;
    const int wn  = w & 3;       // gate strip
    const int wsl = w >> 2;      // K-half select

    // one-time LDS staging that doesn't depend on slot
    for (int i = tid; i < 16384; i += 512) {
        int k = i & 31, d = i >> 5;
        WT4[(k >> 2) * 2048 + d * 4 + (k & 3)] = W_in[i];
    }
    BIN[tid] = b_in[tid];

    // ---- XCD-aware slot claiming (one-shot) ----
    if (tid == 0) {
        const int xcd = __builtin_amdgcn_s_getreg(6164) & 7;  // hwreg(XCC_ID,0,4)
        int idx = aadd(ctrs + 608 + xcd, 1);
        int slot = (idx < 32) ? (xcd * 32 + idx) : -1;
        aadd(ctrs + 576, 1);                                   // grid barrier 1
        while (aload(ctrs + 576) < NBLK) __builtin_amdgcn_s_sleep(1);
        if (slot < 0) {                                        // take r-th leftover
            int rk = aadd(ctrs + 640, 1), acc0 = 0;
            for (int xx = 0; xx < 8; ++xx) {
                int cnt = aload(ctrs + 608 + xx); cnt = (cnt > 32) ? 32 : cnt;
                int left = 32 - cnt;
                if (rk < acc0 + left) { slot = xx * 32 + cnt + (rk - acc0); break; }
                acc0 += left;
            }
        }
        astore(ctrs + 672 + slot, xcd);
        aadd(ctrs + 576, 1);                                   // grid barrier 2
        while (aload(ctrs + 576) < 2 * NBLK) __builtin_amdgcn_s_sleep(1);
        const int Gq = slot >> 4;
        const int u0 = aload(ctrs + 672 + (Gq << 4));
        int fastq = 1;
        for (int i2 = 1; i2 < 16; ++i2)
            fastq &= (aload(ctrs + 672 + (Gq << 4) + i2) == u0);
        sh_si[0] = slot; sh_si[1] = fastq;
    }
    __syncthreads();
    const int slot = sh_si[0];
    const int fast = sh_si[1];
    const int G    = slot >> 4;   // group (batch slice)
    const int m    = slot & 15;   // member (d-strip)
    int* gctr = ctrs + G * 32;

    if (tid < 128) BGT[tid]  = bgate[(tid >> 5) * 512 + m * 32 + (tid & 31)];
    if (tid < 32)  WOUT[tid] = W_out[m * 32 + tid];

    // one-time register weight fragments: N=32 cols (ni*16+r), K-half wsl
    bf16x8 wfrag[16][2];
#pragma unroll
    for (int c = 0; c < 16; ++c)
#pragma unroll
        for (int ni = 0; ni < 2; ++ni) {
            const int j = wn * 512 + m * 32 + ni * 16 + r;
            const int k = wsl * 512 + c * 32 + q * 8;
            wfrag[c][ni] = *(const bf16x8*)(Wcat + (size_t)j * 1024 + k);
        }

    // persistent cell state (registers)
    const int erow = tid >> 3, edg = tid & 7;
    float creg[2][4];
#pragma unroll
    for (int h = 0; h < 2; ++h) {
        const int bg2 = G * 128 + h * 64 + erow;
#pragma unroll
        for (int ii = 0; ii < 4; ++ii)
            creg[h][ii] = c0[(size_t)bg2 * 512 + m * 32 + edg * 4 + ii];
    }
    const float bout0 = b_out[0];
    const int rowbase = G * 128 + m * 8;       // this member's stage-1 rows
    const int xr = tid / 31, xc = tid - xr * 31;

    // prefetch x for t=0 (read-only input: plain cached load)
    float xreg = 0.f;
    if (tid < 248)
        xreg = x[(size_t)(rowbase + xr) * 31 + xc];
    __syncthreads();

    for (int t = 0; t < SEQ; ++t) {
        const bf16_t* Hin  = (t & 1) ? Hb1 : Hb0;
        bf16_t*       Hout = (t & 1) ? Hb0 : Hb1;
        const float*  ysrc = t ? (out + (size_t)(t - 1) * 2048) : y0;
        float*        yt   = out + (size_t)t * 2048;

        bar_wait(gctr, 32 * t);   // y_{t-1} + H from step t-1 visible

        // ---- stage1: X0 rows [rowbase,+8) = relu([x_t,y] @ W_in^T + b_in) --
        if (tid < 248) {
            XS[xr * 32 + xc] = xreg;
        } else if (tid < 256) {
            int rr2 = tid - 248;
            XS[rr2 * 32 + 31] = t ? cloadf(ysrc + rowbase + rr2) : ysrc[rowbase + rr2];
            cstoref(yt + rowbase + rr2, bout0);   // init y with output bias
        }
        __syncthreads();
        {
            const int d = tid;
            const float bi = BIN[d];
            float a0[8];
#pragma unroll
            for (int rr2 = 0; rr2 < 8; ++rr2) a0[rr2] = bi;
#pragma unroll
            for (int k4 = 0; k4 < 8; ++k4) {
                const f32x4 w4 = *(const f32x4*)&WT4[k4 * 2048 + d * 4];
#pragma unroll
                for (int rr2 = 0; rr2 < 8; ++rr2) {
                    const f32x4 x4 = *(const f32x4*)&XS[rr2 * 32 + k4 * 4];
                    a0[rr2] += x4[0] * w4[0] + x4[1] * w4[1] + x4[2] * w4[2] + x4[3] * w4[3];
                }
            }
            // pack (d, d+1) pairs across adjacent lanes -> 4B stores
#pragma unroll
            for (int rr2 = 0; rr2 < 8; ++rr2) {
                float v = fmaxf(a0[rr2], 0.f);
                float o = __shfl_xor(v, 1);
                if ((tid & 1) == 0) {
                    union { struct { bf16_t lo, hi; } s; uint32_t u; } pk;
                    pk.s.lo = (bf16_t)v; pk.s.hi = (bf16_t)o;
                    bf16_t* dst = &X0g[(size_t)(rowbase + rr2) * 512 + d];
                    if (fast) *(uint32_t*)dst = pk.u;     // lands in this XCD's L2
                    else      cstore32(dst, pk.u);        // write through to fabric
                }
            }
        }
        bar_arrive(gctr);                          // -> 32t+16

        // prefetch next step's x slice while others finish stage1
        {
            const int tn = (t + 1 < SEQ) ? (t + 1) : t;
            if (tid < 248)
                xreg = x[(size_t)tn * (2048 * 31) + (size_t)(rowbase + xr) * 31 + xc];
        }
        bar_wait(gctr, 32 * t + 16);               // group's X0 complete

        // ---- stage2: gates GEMM (register-B, LDS-A, XOR bank swizzle) ----
        f32x4 acc[8][2];
#pragma unroll
        for (int mi = 0; mi < 8; ++mi)
#pragma unroll
            for (int ni = 0; ni < 2; ++ni) {
                f32x4 z = {0.f, 0.f, 0.f, 0.f};
                acc[mi][ni] = z;
            }
        const char* ASw = UNI + (wsl ? 16384 : 0);
#pragma unroll
        for (int kt = 0; kt < 8; ++kt) {
            const int lc = (l & 7) ^ ((l >> 3) & 7);
            if (fast) {
#pragma unroll
                for (int i = 0; i < 2; ++i) {
                    const int rowl = i * 64 + w * 8 + (l >> 3);
                    const size_t go = (size_t)(G * 128 + rowl) * 512 + kt * 64 + lc * 8;
                    gload16_sc0(X0g + go, UNI + i * 8192 + w * 1024);
                    gload16_sc0(Hin + go, UNI + 16384 + i * 8192 + w * 1024);
                }
            } else {
#pragma unroll
                for (int i = 0; i < 2; ++i) {
                    const int rowl = i * 64 + w * 8 + (l >> 3);
                    const size_t go = (size_t)(G * 128 + rowl) * 512 + kt * 64 + lc * 8;
                    const uint64_t xa = cload64(X0g + go);
                    const uint64_t xb = cload64(X0g + go + 4);
                    const uint64_t ha = cload64(Hin + go);
                    const uint64_t hb = cload64(Hin + go + 4);
                    uint64_t* d0 = (uint64_t*)(UNI + i * 8192 + w * 1024 + l * 16);
                    d0[0] = xa; d0[1] = xb;
                    uint64_t* d1 = (uint64_t*)(UNI + 16384 + i * 8192 + w * 1024 + l * 16);
                    d1[0] = ha; d1[1] = hb;
                }
            }
            __syncthreads();
#pragma unroll
            for (int c2 = 0; c2 < 2; ++c2) {
                bf16x8 af[8];
#pragma unroll
                for (int mi = 0; mi < 8; ++mi) {
                    const int row = mi * 16 + r;
                    const int ph  = (c2 * 4 + q) ^ (r & 7);
                    af[mi] = *(const bf16x8*)(ASw + row * 128 + ph * 16);
                }
#pragma unroll
                for (int mi = 0; mi < 8; ++mi)
#pragma unroll
                    for (int ni = 0; ni < 2; ++ni)
                        acc[mi][ni] = __builtin_amdgcn_mfma_f32_16x16x32_bf16(
                            af[mi], wfrag[kt * 2 + c2][ni], acc[mi][ni], 0, 0, 0);
            }
            __syncthreads();
        }

        // ---- epilogue: K-half reduce through LDS + fused LSTM cell ----
#pragma unroll
        for (int h = 0; h < 2; ++h) {
#pragma unroll
            for (int mi4 = 0; mi4 < 4; ++mi4) {
                const int mi = h * 4 + mi4;
#pragma unroll
                for (int ni = 0; ni < 2; ++ni)
#pragma unroll
                    for (int rr = 0; rr < 4; ++rr)
                        GS[wsl * GSPLANE + (mi4 * 16 + q * 4 + rr) * 129 + wn * 32 + ni * 16 + r]
                            = acc[mi][ni][rr];
            }
            __syncthreads();
            {
                const int bg2 = G * 128 + h * 64 + erow;
                const float* g0 = GS + erow * 129;
                const float* g1 = GS + GSPLANE + erow * 129;
                float ysum = 0.f;
                union { bf16x4v v; uint64_t u; } hu;
#pragma unroll
                for (int ii = 0; ii < 4; ++ii) {
                    const int dl = edg * 4 + ii;
                    const float gi = g0[dl]      + g1[dl]      + BGT[dl];
                    const float gf = g0[32 + dl] + g1[32 + dl] + BGT[32 + dl];
                    const float gg = g0[64 + dl] + g1[64 + dl] + BGT[64 + dl];
                    const float go = g0[96 + dl] + g1[96 + dl] + BGT[96 + dl];
                    const float cn = sigmoid_f(gf) * creg[h][ii] + sigmoid_f(gi) * tanh_f(gg);
                    creg[h][ii] = cn;
                    const float hval = sigmoid_f(go) * tanh_f(cn);
                    hu.v[ii] = (bf16_t)hval;
                    ysum += hval * WOUT[dl];
                }
                bf16_t* hdst = Hout + (size_t)bg2 * 512 + m * 32 + edg * 4;
                if (fast) *(uint64_t*)hdst = hu.u;
                else      cstore64(hdst, hu.u);
                ysum += __shfl_xor(ysum, 1);
                ysum += __shfl_xor(ysum, 2);
                ysum += __shfl_xor(ysum, 4);
                if (edg == 0) atomicAdd(yt + bg2, ysum);
            }
            __syncthreads();
        }
        bar_arrive(gctr);                          // -> 32t+32
    }
}

// ---------------------------------------------------------------------------
extern "C" void kernel_launch(void* const* d_in, const int* in_sizes, int n_in,
                              void* d_out, int out_size, void* d_ws, size_t ws_size,
                              hipStream_t stream) {
    const float* x     = (const float*)d_in[0];
    const float* h0    = (const float*)d_in[1];
    const float* c0    = (const float*)d_in[2];
    const float* y0    = (const float*)d_in[3];
    const float* W_in  = (const float*)d_in[4];
    const float* b_in  = (const float*)d_in[5];
    const float* W_ih  = (const float*)d_in[6];
    const float* W_hh  = (const float*)d_in[7];
    const float* b_ih  = (const float*)d_in[8];
    const float* b_hh  = (const float*)d_in[9];
    const float* W_out = (const float*)d_in[10];
    const float* b_out = (const float*)d_in[11];
    float* out = (float*)d_out;

    char* ws = (char*)d_ws;
    bf16_t* Wcat  = (bf16_t*)(ws);                  // 4 MiB
    bf16_t* X0    = (bf16_t*)(ws + (4u << 20));     // 2 MiB
    bf16_t* Hb0   = (bf16_t*)(ws + (6u << 20));     // 2 MiB
    bf16_t* Hb1   = (bf16_t*)(ws + (8u << 20));     // 2 MiB
    float*  bgate = (float*)(ws + (10u << 20));     // 8 KiB
    int*    ctrs  = (int*)(ws + (10u << 20) + 8192);// 1024 ints

    prep_w   <<<2048, 256, 0, stream>>>(W_ih, W_hh, Wcat);
    prep_h0  <<<2048, 256, 0, stream>>>(h0, Hb0);
    prep_bias<<<8,    256, 0, stream>>>(b_ih, b_hh, bgate, ctrs);

    hipFuncSetAttribute((const void*)holstm_persist,
                        hipFuncAttributeMaxDynamicSharedMemorySize, SMEM_BYTES);
    void* kargs[] = {
        (void*)&x, (void*)&y0, (void*)&c0, (void*)&W_in, (void*)&b_in, (void*)&b_out,
        (void*)&W_out, (void*)&Wcat, (void*)&bgate, (void*)&X0, (void*)&Hb0, (void*)&Hb1,
        (void*)&out, (void*)&ctrs };
    hipError_t e = hipLaunchCooperativeKernel((const void*)holstm_persist,
                                              dim3(NBLK), dim3(512), kargs,
                                              SMEM_BYTES, stream);
    if (e != hipSuccess) {
        holstm_persist<<<NBLK, 512, SMEM_BYTES, stream>>>(
            x, y0, c0, W_in, b_in, b_out, W_out, Wcat, bgate, X0, Hb0, Hb1, out, ctrs);
    }
    (void)in_sizes; (void)n_in; (void)out_size; (void)ws_size;
}

// Round 6
// 19677.386 us; speedup vs baseline: 1.7742x; 1.7742x over previous
//
#include <hip/hip_runtime.h>
#include <hip/hip_bf16.h>
#include <stdint.h>

#define SEQ   512
#define NBLK  256

typedef __bf16 bf16_t;
typedef bf16_t bf16x8 __attribute__((ext_vector_type(8)));
typedef bf16_t bf16x4v __attribute__((ext_vector_type(4)));
typedef float  f32x4  __attribute__((ext_vector_type(4)));

// ---- dynamic LDS layout (bytes) ----
// SB: 4-deep staging ring, 4 x 32768 (X0-half 16K + H-half 16K per buf).
// GS (2 x 64 x 129 f32 = 66048) aliases SB[0..2) - only live in epilogue,
// when all ring DMAs have retired (kt7 waits vmcnt(0) before its barrier)
// and the only possibly-still-busy buffer is buf3 (98304+), disjoint.
#define OFF_SB    0
#define OFF_XS    131072   // xs f32[8][32]; col 31 = y_prev
#define OFF_BGT   132096   // b_gate strips for this member (4x32)
#define OFF_WOUT  132608   // W_out[m*32..+32]
#define SMEM_BYTES 132736
#define GSPLANE   8256     // floats per Gs plane (64*129)

// ---- device-coherent (agent-scope, relaxed) accessors: sc1, no cache maint -
__device__ __forceinline__ void cstore64(void* p, uint64_t v) {
    __hip_atomic_store((uint64_t*)p, v, __ATOMIC_RELAXED, __HIP_MEMORY_SCOPE_AGENT);
}
__device__ __forceinline__ void cstore32(void* p, uint32_t v) {
    __hip_atomic_store((uint32_t*)p, v, __ATOMIC_RELAXED, __HIP_MEMORY_SCOPE_AGENT);
}
__device__ __forceinline__ void cstoref(float* p, float v) {
    __hip_atomic_store(p, v, __ATOMIC_RELAXED, __HIP_MEMORY_SCOPE_AGENT);
}
__device__ __forceinline__ float cloadf(const float* p) {
    return __hip_atomic_load(p, __ATOMIC_RELAXED, __HIP_MEMORY_SCOPE_AGENT);
}

// global->LDS 16B/lane DMA; aux=1: behaviorally verified (r4/r5 counters) to
// read the coherent point - correct against sc1 write-through producers on
// any XCD. LDS dest = wave-uniform base + lane*16.
__device__ __forceinline__ void gload16_dev(const void* g, void* lds) {
    __builtin_amdgcn_global_load_lds(
        (const __attribute__((address_space(1))) void*)g,
        (__attribute__((address_space(3))) void*)lds, 16, 0, 1);
}

__device__ __forceinline__ float sigmoid_f(float x) { return 1.f / (1.f + __expf(-x)); }
__device__ __forceinline__ float tanh_f(float x)    { float e = __expf(2.f * x); return 1.f - 2.f / (e + 1.f); }

// group-local (16-block) split barrier; relaxed atomics, no cache maintenance.
// __syncthreads() before the add drains every wave's vmem (sc1 stores are
// globally visible once retired).
__device__ __forceinline__ void bar_arrive(int* c) {
    __syncthreads();
    if (threadIdx.x == 0) {
        __builtin_amdgcn_s_waitcnt(0);
        __hip_atomic_fetch_add(c, 1, __ATOMIC_RELAXED, __HIP_MEMORY_SCOPE_AGENT);
    }
}
__device__ __forceinline__ void bar_wait(int* c, int target) {
    if (threadIdx.x == 0) {
        while (__hip_atomic_load(c, __ATOMIC_RELAXED, __HIP_MEMORY_SCOPE_AGENT) < target)
            __builtin_amdgcn_s_sleep(1);
    }
    __syncthreads();
}

// ---------------- prep kernels ----------------
__global__ void prep_w(const float* __restrict__ W_ih, const float* __restrict__ W_hh,
                       bf16_t* __restrict__ Wcat) {
    const int j = blockIdx.x;
    for (int k = threadIdx.x; k < 1024; k += 256) {
        float v = (k < 512) ? W_ih[(size_t)j * 512 + k] : W_hh[(size_t)j * 512 + (k - 512)];
        Wcat[(size_t)j * 1024 + k] = (bf16_t)v;
    }
}
__global__ void prep_h0(const float* __restrict__ h0, bf16_t* __restrict__ H0) {
    const int b = blockIdx.x;
    for (int d = threadIdx.x; d < 512; d += 256)
        H0[(size_t)b * 512 + d] = (bf16_t)h0[(size_t)b * 512 + d];
}
__global__ void prep_bias(const float* __restrict__ b_ih, const float* __restrict__ b_hh,
                          float* __restrict__ bg, int* __restrict__ ctrs) {
    int j = blockIdx.x * 256 + threadIdx.x;
    bg[j] = b_ih[j] + b_hh[j];
    if (j < 1024) ctrs[j] = 0;
}

// ---------------- persistent whole-sequence kernel ----------------
// group G = bid&15 owns batch rows [G*128,+128); member m = bid>>4 owns
// d-strip [m*32,+32) x 4 gates. Stage-2 staging: 4-buffer LDS ring, 16B
// global_load_lds DMA, 3-deep prefetch, raw s_barrier + manual vmcnt(N)
// (never a mid-loop full drain).
__global__ __launch_bounds__(512, 2) void holstm_persist(
    const float* __restrict__ x,     const float* __restrict__ y0,
    const float* __restrict__ c0,    const float* __restrict__ W_in,
    const float* __restrict__ b_in,  const float* __restrict__ b_out,
    const float* __restrict__ W_out, const bf16_t* __restrict__ Wcat,
    const float* __restrict__ bgate, bf16_t* __restrict__ X0g,
    bf16_t* __restrict__ Hb0,        bf16_t* __restrict__ Hb1,
    float* __restrict__ out,         int* __restrict__ ctrs)
{
    extern __shared__ char smem[];
    float* GS   = (float*)(smem + OFF_SB);     // aliases staging ring
    float* XS   = (float*)(smem + OFF_XS);
    float* BGT  = (float*)(smem + OFF_BGT);
    float* WOUT = (float*)(smem + OFF_WOUT);

    const int tid = threadIdx.x;
    const int l   = tid & 63;
    const int w   = tid >> 6;
    const int r   = l & 15;
    const int q   = l >> 4;
    const int wn  = w & 3;       // gate strip
    const int wsl = w >> 2;      // K-half select
    const int bid = blockIdx.x;
    const int G   = bid & 15;    // group (batch slice)
    const int m   = bid >> 4;    // member (d-strip)
    int* gctr = ctrs + G * 32;

    if (tid < 128) BGT[tid]  = bgate[(tid >> 5) * 512 + m * 32 + (tid & 31)];
    if (tid < 32)  WOUT[tid] = W_out[m * 32 + tid];

    // one-time register weight fragments: N=32 cols (ni*16+r), K-half wsl
    bf16x8 wfrag[16][2];
#pragma unroll
    for (int c = 0; c < 16; ++c)
#pragma unroll
        for (int ni = 0; ni < 2; ++ni) {
            const int j = wn * 512 + m * 32 + ni * 16 + r;
            const int k = wsl * 512 + c * 32 + q * 8;
            wfrag[c][ni] = *(const bf16x8*)(Wcat + (size_t)j * 1024 + k);
        }

    // persistent cell state (registers)
    const int erow = tid >> 3, edg = tid & 7;
    float creg[2][4];
#pragma unroll
    for (int h = 0; h < 2; ++h) {
        const int bg2 = G * 128 + h * 64 + erow;
#pragma unroll
        for (int ii = 0; ii < 4; ++ii)
            creg[h][ii] = c0[(size_t)bg2 * 512 + m * 32 + edg * 4 + ii];
    }
    const float bi    = b_in[tid];             // this thread's stage-1 bias
    const float bout0 = b_out[0];
    const int rowbase = G * 128 + m * 8;       // this member's stage-1 rows
    const int xr = tid / 31, xc = tid - xr * 31;
    const float* wrow = W_in + (size_t)tid * 32;  // L2-resident after step 0

    // prefetch x for t=0 (read-only input: plain cached load)
    float xreg = 0.f;
    if (tid < 248)
        xreg = x[(size_t)(rowbase + xr) * 31 + xc];
    __syncthreads();

    for (int t = 0; t < SEQ; ++t) {
        const bf16_t* Hin  = (t & 1) ? Hb1 : Hb0;
        bf16_t*       Hout = (t & 1) ? Hb0 : Hb1;
        const float*  ysrc = t ? (out + (size_t)(t - 1) * 2048) : y0;
        float*        yt   = out + (size_t)t * 2048;

        bar_wait(gctr, 32 * t);   // y_{t-1} + H from step t-1 visible

        // ---- stage1: X0 rows [rowbase,+8) = relu([x_t,y] @ W_in^T + b_in) --
        if (tid < 248) {
            XS[xr * 32 + xc] = xreg;
        } else if (tid < 256) {
            int rr2 = tid - 248;
            XS[rr2 * 32 + 31] = t ? cloadf(ysrc + rowbase + rr2) : ysrc[rowbase + rr2];
            cstoref(yt + rowbase + rr2, bout0);   // init y with output bias
        }
        __syncthreads();
        {
            float a0[8];
#pragma unroll
            for (int rr2 = 0; rr2 < 8; ++rr2) a0[rr2] = bi;
#pragma unroll
            for (int k4 = 0; k4 < 8; ++k4) {
                const f32x4 w4 = *(const f32x4*)&wrow[k4 * 4];
#pragma unroll
                for (int rr2 = 0; rr2 < 8; ++rr2) {
                    const f32x4 x4 = *(const f32x4*)&XS[rr2 * 32 + k4 * 4];
                    a0[rr2] += x4[0] * w4[0] + x4[1] * w4[1] + x4[2] * w4[2] + x4[3] * w4[3];
                }
            }
            // pack (d, d+1) pairs across adjacent lanes -> sc1 4B stores
#pragma unroll
            for (int rr2 = 0; rr2 < 8; ++rr2) {
                float v = fmaxf(a0[rr2], 0.f);
                float o = __shfl_xor(v, 1);
                if ((tid & 1) == 0) {
                    union { struct { bf16_t lo, hi; } s; uint32_t u; } pk;
                    pk.s.lo = (bf16_t)v; pk.s.hi = (bf16_t)o;
                    cstore32(&X0g[(size_t)(rowbase + rr2) * 512 + tid], pk.u);
                }
            }
        }
        bar_arrive(gctr);                          // -> 32t+16

        // prefetch next step's x slice while others finish stage1
        {
            const int tn = (t + 1 < SEQ) ? (t + 1) : t;
            if (tid < 248)
                xreg = x[(size_t)tn * (2048 * 31) + (size_t)(rowbase + xr) * 31 + xc];
        }
        bar_wait(gctr, 32 * t + 16);               // group's X0 complete

        // ---- stage2: pipelined gates GEMM (register-B, LDS-ring A) ----
        f32x4 acc[8][2];
#pragma unroll
        for (int mi = 0; mi < 8; ++mi)
#pragma unroll
            for (int ni = 0; ni < 2; ++ni) {
                f32x4 z = {0.f, 0.f, 0.f, 0.f};
                acc[mi][ni] = z;
            }

        const int lc = (l & 7) ^ ((l >> 3) & 7);
        auto issue_kt = [&](int ktI) {
            char* SBb = smem + (ktI & 3) * 32768;
#pragma unroll
            for (int i = 0; i < 2; ++i) {
                const int rowl = i * 64 + w * 8 + (l >> 3);
                const size_t go = (size_t)(G * 128 + rowl) * 512 + ktI * 64 + lc * 8;
                gload16_dev(X0g + go, SBb + i * 8192 + w * 1024);
                gload16_dev(Hin + go, SBb + 16384 + i * 8192 + w * 1024);
            }
        };

        // drain stage-1 stores/loads so manual vmcnt counts only ring DMAs
        asm volatile("s_waitcnt vmcnt(0)" ::: "memory");
        issue_kt(0); issue_kt(1); issue_kt(2);     // 12 loads in flight

#pragma unroll
        for (int kt = 0; kt < 8; ++kt) {
            // wait for THIS wave's buf[kt] (oldest 4), keep the rest in flight
            if (kt < 6)       asm volatile("s_waitcnt vmcnt(8)" ::: "memory");
            else if (kt == 6) asm volatile("s_waitcnt vmcnt(4)" ::: "memory");
            else              asm volatile("s_waitcnt vmcnt(0)" ::: "memory");
            asm volatile("s_barrier" ::: "memory");  // all waves' buf[kt] landed
            if (kt < 5) issue_kt(kt + 3);            // refill ring 3 ahead
            const char* ASw = smem + (kt & 3) * 32768 + (wsl ? 16384 : 0);
#pragma unroll
            for (int c2 = 0; c2 < 2; ++c2) {
                bf16x8 af[8];
#pragma unroll
                for (int mi = 0; mi < 8; ++mi) {
                    const int row = mi * 16 + r;
                    const int ph  = (c2 * 4 + q) ^ (r & 7);
                    af[mi] = *(const bf16x8*)(ASw + row * 128 + ph * 16);
                }
#pragma unroll
                for (int mi = 0; mi < 8; ++mi)
#pragma unroll
                    for (int ni = 0; ni < 2; ++ni)
                        acc[mi][ni] = __builtin_amdgcn_mfma_f32_16x16x32_bf16(
                            af[mi], wfrag[kt * 2 + c2][ni], acc[mi][ni], 0, 0, 0);
            }
        }
        __syncthreads();   // all waves done with ring before GS overwrites it

        // ---- epilogue: K-half reduce through LDS + fused LSTM cell ----
#pragma unroll
        for (int h = 0; h < 2; ++h) {
#pragma unroll
            for (int mi4 = 0; mi4 < 4; ++mi4) {
                const int mi = h * 4 + mi4;
#pragma unroll
                for (int ni = 0; ni < 2; ++ni)
#pragma unroll
                    for (int rr = 0; rr < 4; ++rr)
                        GS[wsl * GSPLANE + (mi4 * 16 + q * 4 + rr) * 129 + wn * 32 + ni * 16 + r]
                            = acc[mi][ni][rr];
            }
            __syncthreads();
            {
                const int bg2 = G * 128 + h * 64 + erow;
                const float* g0 = GS + erow * 129;
                const float* g1 = GS + GSPLANE + erow * 129;
                float ysum = 0.f;
                union { bf16x4v v; uint64_t u; } hu;
#pragma unroll
                for (int ii = 0; ii < 4; ++ii) {
                    const int dl = edg * 4 + ii;
                    const float gi = g0[dl]      + g1[dl]      + BGT[dl];
                    const float gf = g0[32 + dl] + g1[32 + dl] + BGT[32 + dl];
                    const float gg = g0[64 + dl] + g1[64 + dl] + BGT[64 + dl];
                    const float go = g0[96 + dl] + g1[96 + dl] + BGT[96 + dl];
                    const float cn = sigmoid_f(gf) * creg[h][ii] + sigmoid_f(gi) * tanh_f(gg);
                    creg[h][ii] = cn;
                    const float hval = sigmoid_f(go) * tanh_f(cn);
                    hu.v[ii] = (bf16_t)hval;
                    ysum += hval * WOUT[dl];
                }
                cstore64(Hout + (size_t)bg2 * 512 + m * 32 + edg * 4, hu.u);
                ysum += __shfl_xor(ysum, 1);
                ysum += __shfl_xor(ysum, 2);
                ysum += __shfl_xor(ysum, 4);
                if (edg == 0) atomicAdd(yt + bg2, ysum);
            }
            __syncthreads();
        }
        bar_arrive(gctr);                          // -> 32t+32
    }
}

// ---------------------------------------------------------------------------
extern "C" void kernel_launch(void* const* d_in, const int* in_sizes, int n_in,
                              void* d_out, int out_size, void* d_ws, size_t ws_size,
                              hipStream_t stream) {
    const float* x     = (const float*)d_in[0];
    const float* h0    = (const float*)d_in[1];
    const float* c0    = (const float*)d_in[2];
    const float* y0    = (const float*)d_in[3];
    const float* W_in  = (const float*)d_in[4];
    const float* b_in  = (const float*)d_in[5];
    const float* W_ih  = (const float*)d_in[6];
    const float* W_hh  = (const float*)d_in[7];
    const float* b_ih  = (const float*)d_in[8];
    const float* b_hh  = (const float*)d_in[9];
    const float* W_out = (const float*)d_in[10];
    const float* b_out = (const float*)d_in[11];
    float* out = (float*)d_out;

    char* ws = (char*)d_ws;
    bf16_t* Wcat  = (bf16_t*)(ws);                  // 4 MiB
    bf16_t* X0    = (bf16_t*)(ws + (4u << 20));     // 2 MiB
    bf16_t* Hb0   = (bf16_t*)(ws + (6u << 20));     // 2 MiB
    bf16_t* Hb1   = (bf16_t*)(ws + (8u << 20));     // 2 MiB
    float*  bgate = (float*)(ws + (10u << 20));     // 8 KiB
    int*    ctrs  = (int*)(ws + (10u << 20) + 8192);// 1024 ints

    prep_w   <<<2048, 256, 0, stream>>>(W_ih, W_hh, Wcat);
    prep_h0  <<<2048, 256, 0, stream>>>(h0, Hb0);
    prep_bias<<<8,    256, 0, stream>>>(b_ih, b_hh, bgate, ctrs);

    hipFuncSetAttribute((const void*)holstm_persist,
                        hipFuncAttributeMaxDynamicSharedMemorySize, SMEM_BYTES);
    void* kargs[] = {
        (void*)&x, (void*)&y0, (void*)&c0, (void*)&W_in, (void*)&b_in, (void*)&b_out,
        (void*)&W_out, (void*)&Wcat, (void*)&bgate, (void*)&X0, (void*)&Hb0, (void*)&Hb1,
        (void*)&out, (void*)&ctrs };
    hipError_t e = hipLaunchCooperativeKernel((const void*)holstm_persist,
                                              dim3(NBLK), dim3(512), kargs,
                                              SMEM_BYTES, stream);
    if (e != hipSuccess) {
        holstm_persist<<<NBLK, 512, SMEM_BYTES, stream>>>(
            x, y0, c0, W_in, b_in, b_out, W_out, Wcat, bgate, X0, Hb0, Hb1, out, ctrs);
    }
    (void)in_sizes; (void)n_in; (void)out_size; (void)ws_size;
}